// Round 16
// baseline (95.627 us; speedup 1.0000x reference)
//
#include <hip/hip_runtime.h>
#include <math.h>

#define NB 2
#define NL 4096
#define NS 4096
#define NH 8
#define NE 64
#define ND 64
#define SB 64
#define NT (NS / SB)
#define GT (NT / 2)            // tiles per warp-group (S split in 2)
#define TILE_B 8192            // one 64x64 bf16 tile image, bytes
#define LOG2E 1.4426950408889634f
#define SC2 (0.125f * LOG2E)   // scale * log2(e), folded into Q

typedef __attribute__((ext_vector_type(8))) short bf16x8;
typedef __attribute__((ext_vector_type(4))) float f32x4;
typedef __attribute__((ext_vector_type(16))) float f32x16;
typedef unsigned short ushort_t;

__device__ __forceinline__ short f2bf(float f) {
  union { float f; unsigned u; } v; v.f = f;
  unsigned u = v.u;
  return (short)((u + 0x7fffu + ((u >> 16) & 1u)) >> 16);
}

__device__ __forceinline__ unsigned cvt_pk_bf16(float lo, float hi) {
  unsigned r;
  asm("v_cvt_pk_bf16_f32 %0, %1, %2" : "=v"(r) : "v"(lo), "v"(hi));
  return r;
}

__device__ __forceinline__ void gload16(const void* g, void* l) {
  __builtin_amdgcn_global_load_lds(
      (const __attribute__((address_space(1))) void*)g,
      (__attribute__((address_space(3))) void*)l, 16, 0, 0);
}

// Fragment-ordered tile image layout (both K and V^T tiles):
//   byte_off(kk, j, h, lq) = kk*2048 + j*1024 + h*512 + lq*16
// A wave's fragment read (kk,j) covers 1024 contiguous bytes -> conflict-free.

// ---- fused prep: K -> bf16 images ; V -> exp(V) (no vmax: cancels in the
// log-domain epilogue), transposed [d][s], fragment-ordered images ----
__global__ __launch_bounds__(256) void kvprep(const float* __restrict__ Kg,
                                              const float* __restrict__ Vg,
                                              ushort_t* __restrict__ kimg,
                                              ushort_t* __restrict__ vimg) {
  int blk = blockIdx.x;              // 1024 = bh*64 + tile
  int bh = blk >> 6, tile = blk & 63;
  int b = bh >> 3, h = bh & 7;
  int t = threadIdx.x;
  int srow = t >> 2, c16 = (t & 3) * 16;
  {  // K
    const float4* p4 =
        (const float4*)(Kg + (((size_t)b * NS + tile * SB + srow) * NH + h) * NE + c16);
    float4 a = p4[0], bq = p4[1], c = p4[2], d = p4[3];
    unsigned u0 = cvt_pk_bf16(a.x, a.y), u1 = cvt_pk_bf16(a.z, a.w);
    unsigned u2 = cvt_pk_bf16(bq.x, bq.y), u3 = cvt_pk_bf16(bq.z, bq.w);
    unsigned u4 = cvt_pk_bf16(c.x, c.y), u5 = cvt_pk_bf16(c.z, c.w);
    unsigned u6 = cvt_pk_bf16(d.x, d.y), u7 = cvt_pk_bf16(d.z, d.w);
    char* base = (char*)kimg + (size_t)blk * TILE_B;
    int off0 = (c16 >> 4) * 2048 + (srow >> 5) * 1024 + (srow & 31) * 16;
    uint4 w0 = {u0, u1, u2, u3}, w1 = {u4, u5, u6, u7};
    *(uint4*)(base + off0) = w0;
    *(uint4*)(base + off0 + 512) = w1;
  }
  {  // V: exp(V), transpose via LDS, fragment-ordered
    __shared__ short Vsh[64 * 72];   // [d][s], stride 72 shorts
    const float4* p4 =
        (const float4*)(Vg + (((size_t)b * NS + tile * SB + srow) * NH + h) * ND + c16);
    float4 va = p4[0], vb = p4[1], vc = p4[2], vd = p4[3];
    float fv[16] = {va.x, va.y, va.z, va.w, vb.x, vb.y, vb.z, vb.w,
                    vc.x, vc.y, vc.z, vc.w, vd.x, vd.y, vd.z, vd.w};
#pragma unroll
    for (int i = 0; i < 16; ++i)
      Vsh[(c16 + i) * 72 + srow] = f2bf(__expf(fv[i]));
    __syncthreads();
    int dr = t >> 2, sc = (t & 3) * 16;
    bf16x8 o0 = *(const bf16x8*)&Vsh[dr * 72 + sc];
    bf16x8 o1 = *(const bf16x8*)&Vsh[dr * 72 + sc + 8];
    char* base = (char*)vimg + (size_t)blk * TILE_B;
    int off0 = (sc >> 4) * 2048 + (dr >> 5) * 1024 + (dr & 31) * 16;
    *(bf16x8*)(base + off0) = o0;
    *(bf16x8*)(base + off0 + 512) = o1;
  }
}

// ---- main kernel: swapped-QK^T 32x32 MFMA, S-split x2, K+V LDS dbuf,
// softmax denominator via MFMA-with-ones (l in accumulator row layout) ----
// Block = (b,h, 128 q-rows), 8 warps: grp0 tiles 0..31, grp1 tiles 32..63.
__global__ __launch_bounds__(512) void laser_fast(
    const float* __restrict__ Qg, const ushort_t* __restrict__ Kimg,
    const ushort_t* __restrict__ Vimg, float* __restrict__ Og) {
  int orig = blockIdx.x;
  int bid = (orig & 7) * 64 + (orig >> 3);   // bijective XCD swizzle (512%8==0)
  int qt = bid & 31;                         // 32 q-tiles of 128
  int bh = bid >> 5;
  int b = bh >> 3, hh = bh & 7;
  int t = threadIdx.x;
  int w = t >> 6;        // warp 0..7
  int grp = w >> 2;      // S-chunk group
  int wi = w & 3;        // q-subtile within block
  int lane = t & 63;
  int lq = lane & 31;    // q-col in QK^T, d-col in PV
  int h = lane >> 5;     // lane half

  __shared__ __attribute__((aligned(16))) char smem[65536];
  // K tiles: grp g, buf b -> smem + g*16384 + b*8192 ; V at +32768.
  char* kls = smem + grp * 16384;
  char* vls = smem + 32768 + grp * 16384;

  const char* kbase = (const char*)Kimg + (size_t)bh * (NT * TILE_B);
  const char* vbase = (const char*)Vimg + (size_t)bh * (NT * TILE_B);

  // Q' fragments: B-operand, lane holds Q'[q=lq][e = 16kk + 8h + j], pre-scaled
  int q0 = qt * 128 + wi * 32;
  const float* qp = Qg + (((size_t)b * NL + q0 + lq) * NH + hh) * NE;
  bf16x8 qf[4];
#pragma unroll
  for (int kk = 0; kk < 4; ++kk) {
    int e0 = 16 * kk + 8 * h;
    float4 x = *(const float4*)(qp + e0);
    float4 y = *(const float4*)(qp + e0 + 4);
    union { bf16x8 v; unsigned u[4]; } tm;
    tm.u[0] = cvt_pk_bf16(x.x * SC2, x.y * SC2);
    tm.u[1] = cvt_pk_bf16(x.z * SC2, x.w * SC2);
    tm.u[2] = cvt_pk_bf16(y.x * SC2, y.y * SC2);
    tm.u[3] = cvt_pk_bf16(y.z * SC2, y.w * SC2);
    qf[kk] = tm.v;
  }

  // ones fragment (bf16 1.0) for the l-sum MFMA
  bf16x8 onesf;
#pragma unroll
  for (int i = 0; i < 8; ++i) onesf[i] = (short)0x3F80;

  f32x16 acc0, acc1, lacc;
#pragma unroll
  for (int i = 0; i < 16; ++i) { acc0[i] = 0.f; acc1[i] = 0.f; lacc[i] = 0.f; }

  int soff = wi * 2048 + lane * 16;  // staging offset within tile image
  int tbase = grp * GT;              // group's first tile
  int fb = h * 512 + lq * 16;        // per-lane fragment base

#define STAGE(buf, ti)                                                       \
  do {                                                                       \
    const char* ks = kbase + (size_t)(tbase + (ti)) * TILE_B + soff;         \
    const char* vs = vbase + (size_t)(tbase + (ti)) * TILE_B + soff;         \
    gload16(ks, kls + (buf) * 8192 + wi * 2048);                             \
    gload16(ks + 1024, kls + (buf) * 8192 + wi * 2048 + 1024);               \
    gload16(vs, vls + (buf) * 8192 + wi * 2048);                             \
    gload16(vs + 1024, vls + (buf) * 8192 + wi * 2048 + 1024);               \
  } while (0)

#define MAKE_PA(P, g, idx)                                                   \
    do {                                                                     \
      unsigned a0 = cvt_pk_bf16(P[8 * (g) + 0], P[8 * (g) + 1]);             \
      unsigned a1 = cvt_pk_bf16(P[8 * (g) + 2], P[8 * (g) + 3]);             \
      unsigned b0 = cvt_pk_bf16(P[8 * (g) + 4], P[8 * (g) + 5]);             \
      unsigned b1 = cvt_pk_bf16(P[8 * (g) + 6], P[8 * (g) + 7]);             \
      auto w02 = __builtin_amdgcn_permlane32_swap(a0, b0, false, false);     \
      auto w13 = __builtin_amdgcn_permlane32_swap(a1, b1, false, false);     \
      union { bf16x8 v; unsigned u[4]; } tm;                                 \
      tm.u[0] = w02[0]; tm.u[1] = w13[0]; tm.u[2] = w02[1]; tm.u[3] = w13[1];\
      pa[idx] = tm.v;                                                        \
    } while (0)

  STAGE(0, 0);
  asm volatile("s_waitcnt vmcnt(0)" ::: "memory");
  __syncthreads();
  int cur = 0;

  for (int ti = 0; ti < GT; ++ti) {
    if (ti + 1 < GT) STAGE(cur ^ 1, ti + 1);

    const char* Kc = kls + cur * 8192;
    const char* Vc = vls + cur * 8192;

    // QK^T (swapped): S^T = K * Q'^T. Lane holds S[s=crow(r,h)][q=lq].
    f32x16 s0, s1;
#pragma unroll
    for (int i = 0; i < 16; ++i) { s0[i] = 0.f; s1[i] = 0.f; }
    __builtin_amdgcn_s_setprio(1);
#pragma unroll
    for (int kk = 0; kk < 4; ++kk) {
      bf16x8 ka = *(const bf16x8*)(Kc + fb + kk * 2048);
      bf16x8 kb = *(const bf16x8*)(Kc + fb + kk * 2048 + 1024);
      s0 = __builtin_amdgcn_mfma_f32_32x32x16_bf16(ka, qf[kk], s0, 0, 0, 0);
      s1 = __builtin_amdgcn_mfma_f32_32x32x16_bf16(kb, qf[kk], s1, 0, 0, 0);
    }
    __builtin_amdgcn_s_setprio(0);

    // P = exp2(S') (Q pre-scaled; no max subtraction needed)
#pragma unroll
    for (int i = 0; i < 16; ++i) {
      s0[i] = __builtin_amdgcn_exp2f(s0[i]);
      s1[i] = __builtin_amdgcn_exp2f(s1[i]);
    }

    // P -> PV A-fragments: 16 cvt_pk + 8 permlane32_swap, no LDS roundtrip.
    bf16x8 pa[4];
    MAKE_PA(s0, 0, 0);
    MAKE_PA(s0, 1, 1);
    MAKE_PA(s1, 0, 2);
    MAKE_PA(s1, 1, 3);

    // PV: O += P * Vexp ; l += P * ones (row-sum on the MFMA pipe, result
    // already in accumulator row layout: lacc[r] = l[q=crow(r,h)])
    __builtin_amdgcn_s_setprio(1);
#pragma unroll
    for (int kk = 0; kk < 4; ++kk) {
      bf16x8 v0 = *(const bf16x8*)(Vc + fb + kk * 2048);
      bf16x8 v1 = *(const bf16x8*)(Vc + fb + kk * 2048 + 1024);
      acc0 = __builtin_amdgcn_mfma_f32_32x32x16_bf16(pa[kk], v0, acc0, 0, 0, 0);
      acc1 = __builtin_amdgcn_mfma_f32_32x32x16_bf16(pa[kk], v1, acc1, 0, 0, 0);
      lacc = __builtin_amdgcn_mfma_f32_32x32x16_bf16(pa[kk], onesf, lacc, 0, 0, 0);
    }
    __builtin_amdgcn_s_setprio(0);

    asm volatile("s_waitcnt vmcnt(0)" ::: "memory");
    __syncthreads();
    cur ^= 1;
  }
#undef STAGE
#undef MAKE_PA

  // ---- combine the two S-chunk partials (plain sums) via LDS ----
  // K/V buffers are dead after the final barrier above; reuse smem.
  float* exch = (float*)(void*)smem;   // per wi: 48 vals x 64 lanes (48KB)
  if (grp == 1) {
    float* e = exch + wi * 3072 + lane;
#pragma unroll
    for (int r = 0; r < 16; ++r) {
      e[r * 64] = acc0[r];
      e[(16 + r) * 64] = acc1[r];
      e[(32 + r) * 64] = lacc[r];
    }
  }
  __syncthreads();
  if (grp == 0) {
    float* e = exch + wi * 3072 + lane;
#pragma unroll
    for (int r = 0; r < 16; ++r) {
      acc0[r] += e[r * 64];
      acc1[r] += e[(16 + r) * 64];
      lacc[r] += e[(32 + r) * 64];
    }

    // out = log(O) - log(l[q]) ; vmax cancels exactly in log domain.
    // lacc[r] is already l for q=crow(r,h) -- no redistribution needed.
#pragma unroll
    for (int r = 0; r < 16; ++r) {
      int q = (r & 3) + 8 * (r >> 2) + 4 * h;
      float logl = __logf(lacc[r]);
      size_t o = (((size_t)b * NL + q0 + q) * NH + hh) * ND + lq;
      Og[o] = __logf(acc0[r]) - logl;
      Og[o + 32] = __logf(acc1[r]) - logl;
    }
  }
}

// ---- slow fallback path (self-contained, needs vmax) ----
__global__ void vmax_partial(const float* __restrict__ Vp, float* __restrict__ part) {
  int blk = blockIdx.x;
  int bh = blk >> 4, ck = blk & 15;
  int b = bh >> 3, h = bh & 7;
  int t = threadIdx.x;
  int d = t & 63, g = t >> 6;
  const float* base = Vp + (((size_t)b * NS + ck * 256) * NH + h) * ND + d;
  float m = -INFINITY;
  for (int s = g; s < 256; s += 4)
    m = fmaxf(m, base[(size_t)s * NH * ND]);
  __shared__ float red[4][64];
  red[g][d] = m;
  __syncthreads();
  if (t < 64)
    part[(size_t)blk * 64 + t] =
        fmaxf(fmaxf(red[0][t], red[1][t]), fmaxf(red[2][t], red[3][t]));
}

__global__ void vmax_reduce(const float* __restrict__ part, float* __restrict__ vmax) {
  int bh = blockIdx.x, t = threadIdx.x;
  float m = -INFINITY;
#pragma unroll
  for (int c = 0; c < 16; ++c)
    m = fmaxf(m, part[((size_t)bh * 16 + c) * 64 + t]);
  vmax[bh * 64 + t] = m;
}

__global__ __launch_bounds__(256) void laser_slow(
    const float* __restrict__ Qg, const float* __restrict__ Kg,
    const float* __restrict__ Vg, const float* __restrict__ vmax,
    float* __restrict__ Og) {
  int bid = blockIdx.x;
  int qt = bid & 63;
  int bh = bid >> 6;
  int b = bh >> 3, h = bh & 7;
  int t = threadIdx.x;
  int w = t >> 6;
  int lane = t & 63;
  int lr = lane & 15;
  int lg = lane >> 4;

  __shared__ short Kt[SB * NE];
  __shared__ short Vt[ND * SB];
  __shared__ short Pl[4][16 * SB];
  __shared__ float vmx[ND];

  if (t < ND) vmx[t] = vmax[bh * ND + t];

  int q0 = qt * 64;
  int qrow = q0 + w * 16 + lr;
  const float* qptr = Qg + (((size_t)b * NL + qrow) * NH + h) * NE;
  bf16x8 qf[2];
#pragma unroll
  for (int kf = 0; kf < 2; ++kf) {
    const float4* p4 = (const float4*)(qptr + kf * 32 + lg * 8);
    float4 a = p4[0], bq = p4[1];
    qf[kf][0] = f2bf(a.x);  qf[kf][1] = f2bf(a.y);
    qf[kf][2] = f2bf(a.z);  qf[kf][3] = f2bf(a.w);
    qf[kf][4] = f2bf(bq.x); qf[kf][5] = f2bf(bq.y);
    qf[kf][6] = f2bf(bq.z); qf[kf][7] = f2bf(bq.w);
  }

  f32x4 acc_o[4];
  float m_r[4], l_r[4];
  const f32x4 fzero = {0.f, 0.f, 0.f, 0.f};
#pragma unroll
  for (int i = 0; i < 4; ++i) { acc_o[i] = fzero; m_r[i] = -INFINITY; l_r[i] = 0.f; }

  const float scale = 0.125f;
  int srow = t >> 2;
  int c16 = (t & 3) * 16;

  for (int s0 = 0; s0 < NS; s0 += SB) {
    __syncthreads();
    {
      const float4* kp4 =
          (const float4*)(Kg + (((size_t)b * NS + (s0 + srow)) * NH + h) * NE + c16);
      float4 t0 = kp4[0], t1 = kp4[1], t2 = kp4[2], t3 = kp4[3];
      bf16x8 c0, c1;
      c0[0] = f2bf(t0.x); c0[1] = f2bf(t0.y); c0[2] = f2bf(t0.z); c0[3] = f2bf(t0.w);
      c0[4] = f2bf(t1.x); c0[5] = f2bf(t1.y); c0[6] = f2bf(t1.z); c0[7] = f2bf(t1.w);
      c1[0] = f2bf(t2.x); c1[1] = f2bf(t2.y); c1[2] = f2bf(t2.z); c1[3] = f2bf(t2.w);
      c1[4] = f2bf(t3.x); c1[5] = f2bf(t3.y); c1[6] = f2bf(t3.z); c1[7] = f2bf(t3.w);
      int base = srow * 128 + c16 * 2;
      int swz = (srow & 7) << 4;
      *(bf16x8*)((char*)Kt + ((base) ^ swz)) = c0;
      *(bf16x8*)((char*)Kt + ((base + 16) ^ swz)) = c1;
    }
    {
      const float4* vp4 =
          (const float4*)(Vg + (((size_t)b * NS + (s0 + srow)) * NH + h) * ND + c16);
      float4 t0 = vp4[0], t1 = vp4[1], t2 = vp4[2], t3 = vp4[3];
      float fv[16] = {t0.x, t0.y, t0.z, t0.w, t1.x, t1.y, t1.z, t1.w,
                      t2.x, t2.y, t2.z, t2.w, t3.x, t3.y, t3.z, t3.w};
#pragma unroll
      for (int i = 0; i < 16; ++i) {
        int d = c16 + i;
        int byte = (d * 128 + srow * 2) ^ ((d & 7) << 4);
        *(short*)((char*)Vt + byte) = f2bf(__expf(fv[i] - vmx[d]));
      }
    }
    __syncthreads();

    f32x4 sacc[4];
#pragma unroll
    for (int jt = 0; jt < 4; ++jt) sacc[jt] = fzero;
#pragma unroll
    for (int jt = 0; jt < 4; ++jt) {
      int srw = jt * 16 + lr;
      int rb = srw * 128;
      int swz = (srw & 7) << 4;
      bf16x8 kb0 = *(const bf16x8*)((const char*)Kt + ((rb + lg * 16) ^ swz));
      bf16x8 kb1 = *(const bf16x8*)((const char*)Kt + ((rb + 64 + lg * 16) ^ swz));
      sacc[jt] = __builtin_amdgcn_mfma_f32_16x16x32_bf16(qf[0], kb0, sacc[jt], 0, 0, 0);
      sacc[jt] = __builtin_amdgcn_mfma_f32_16x16x32_bf16(qf[1], kb1, sacc[jt], 0, 0, 0);
    }

    float mnew[4], corr[4];
#pragma unroll
    for (int r = 0; r < 4; ++r) {
      float x = fmaxf(fmaxf(sacc[0][r], sacc[1][r]),
                      fmaxf(sacc[2][r], sacc[3][r])) * scale;
      x = fmaxf(x, __shfl_xor(x, 1));
      x = fmaxf(x, __shfl_xor(x, 2));
      x = fmaxf(x, __shfl_xor(x, 4));
      x = fmaxf(x, __shfl_xor(x, 8));
      mnew[r] = fmaxf(m_r[r], x);
      corr[r] = __expf(m_r[r] - mnew[r]);
    }
    float rs[4] = {0.f, 0.f, 0.f, 0.f};
    short pb[4][4];
#pragma unroll
    for (int jt = 0; jt < 4; ++jt)
#pragma unroll
      for (int r = 0; r < 4; ++r) {
        float p = __expf(sacc[jt][r] * scale - mnew[r]);
        rs[r] += p;
        pb[jt][r] = f2bf(p);
      }
#pragma unroll
    for (int r = 0; r < 4; ++r) {
      float x = rs[r];
      x += __shfl_xor(x, 1);
      x += __shfl_xor(x, 2);
      x += __shfl_xor(x, 4);
      x += __shfl_xor(x, 8);
      l_r[r] = l_r[r] * corr[r] + x;
      m_r[r] = mnew[r];
    }
    short* pwv = &Pl[w][0];
#pragma unroll
    for (int jt = 0; jt < 4; ++jt)
#pragma unroll
      for (int r = 0; r < 4; ++r) {
        int row = lg * 4 + r, col = jt * 16 + lr;
        int byte = (row * 128 + col * 2) ^ ((row & 7) << 4);
        *(short*)((char*)pwv + byte) = pb[jt][r];
      }
#pragma unroll
    for (int dt = 0; dt < 4; ++dt)
#pragma unroll
      for (int r = 0; r < 4; ++r) acc_o[dt][r] *= corr[r];
#pragma unroll
    for (int kf = 0; kf < 2; ++kf) {
      int ab = lr * 128;
      int aswz = (lr & 7) << 4;
      bf16x8 pa = *(const bf16x8*)((const char*)pwv + ((ab + kf * 64 + lg * 16) ^ aswz));
#pragma unroll
      for (int dt = 0; dt < 4; ++dt) {
        int drow = dt * 16 + lr;
        int vb_byte = (drow * 128 + kf * 64 + lg * 16) ^ ((drow & 7) << 4);
        bf16x8 vb = *(const bf16x8*)((const char*)Vt + vb_byte);
        acc_o[dt] = __builtin_amdgcn_mfma_f32_16x16x32_bf16(pa, vb, acc_o[dt], 0, 0, 0);
      }
    }
  }

#pragma unroll
  for (int r = 0; r < 4; ++r) {
    int row = q0 + w * 16 + lg * 4 + r;
    float logl = __logf(l_r[r]);
#pragma unroll
    for (int dt = 0; dt < 4; ++dt) {
      int d = dt * 16 + lr;
      Og[(((size_t)b * NL + row) * NH + h) * ND + d] =
          __logf(acc_o[dt][r]) - logl + vmx[d];
    }
  }
}

extern "C" void kernel_launch(void* const* d_in, const int* in_sizes, int n_in,
                              void* d_out, int out_size, void* d_ws, size_t ws_size,
                              hipStream_t stream) {
  (void)in_sizes; (void)n_in; (void)out_size;
  const float* Q = (const float*)d_in[0];
  const float* K = (const float*)d_in[1];
  const float* V = (const float*)d_in[2];
  float* out = (float*)d_out;

  float* vmax = (float*)d_ws;                         // 4KB (slow path only)
  float* part = (float*)((char*)d_ws + 4096);         // 64KB (slow path only)
  const size_t kimg_off = 1u << 20;                   // 1MB
  const size_t vimg_off = (size_t)9u << 20;           // 9MB
  const size_t img_bytes = (size_t)16 * NT * TILE_B;  // 8MB each
  bool fast = ws_size >= vimg_off + img_bytes;

  if (fast) {
    ushort_t* kimg = (ushort_t*)((char*)d_ws + kimg_off);
    ushort_t* vimg = (ushort_t*)((char*)d_ws + vimg_off);
    kvprep<<<dim3(1024), dim3(256), 0, stream>>>(K, V, kimg, vimg);
    laser_fast<<<dim3(512), dim3(512), 0, stream>>>(Q, kimg, vimg, out);
  } else {
    vmax_partial<<<dim3(256), dim3(256), 0, stream>>>(V, part);
    vmax_reduce<<<dim3(16), dim3(64), 0, stream>>>(part, vmax);
    laser_slow<<<dim3(1024), dim3(256), 0, stream>>>(Q, K, V, vmax, out);
  }
}

// Round 17
// 92.686 us; speedup vs baseline: 1.0317x; 1.0317x over previous
//
#include <hip/hip_runtime.h>
#include <math.h>

#define NB 2
#define NL 4096
#define NS 4096
#define NH 8
#define NE 64
#define ND 64
#define SB 64
#define NT (NS / SB)
#define GT (NT / 2)            // tiles per warp-group (S split in 2)
#define TILE_B 8192            // one 64x64 bf16 tile image, bytes
#define LOG2E 1.4426950408889634f
#define SC2 (0.125f * LOG2E)   // scale * log2(e), folded into Q

typedef __attribute__((ext_vector_type(8))) short bf16x8;
typedef __attribute__((ext_vector_type(4))) float f32x4;
typedef __attribute__((ext_vector_type(16))) float f32x16;
typedef unsigned short ushort_t;

__device__ __forceinline__ short f2bf(float f) {
  union { float f; unsigned u; } v; v.f = f;
  unsigned u = v.u;
  return (short)((u + 0x7fffu + ((u >> 16) & 1u)) >> 16);
}

__device__ __forceinline__ unsigned cvt_pk_bf16(float lo, float hi) {
  unsigned r;
  asm("v_cvt_pk_bf16_f32 %0, %1, %2" : "=v"(r) : "v"(lo), "v"(hi));
  return r;
}

__device__ __forceinline__ void gload16(const void* g, void* l) {
  __builtin_amdgcn_global_load_lds(
      (const __attribute__((address_space(1))) void*)g,
      (__attribute__((address_space(3))) void*)l, 16, 0, 0);
}

// Fragment-ordered tile image layout (both K and V^T tiles):
//   byte_off(kk, j, h, lq) = kk*2048 + j*1024 + h*512 + lq*16
// A wave's fragment read (kk,j) covers 1024 contiguous bytes -> conflict-free.

// ---- fused prep: K -> bf16 images ; V -> exp(V) (no vmax: cancels in the
// log-domain epilogue), transposed [d][s], fragment-ordered images ----
__global__ __launch_bounds__(256) void kvprep(const float* __restrict__ Kg,
                                              const float* __restrict__ Vg,
                                              ushort_t* __restrict__ kimg,
                                              ushort_t* __restrict__ vimg) {
  int blk = blockIdx.x;              // 1024 = bh*64 + tile
  int bh = blk >> 6, tile = blk & 63;
  int b = bh >> 3, h = bh & 7;
  int t = threadIdx.x;
  int srow = t >> 2, c16 = (t & 3) * 16;
  {  // K
    const float4* p4 =
        (const float4*)(Kg + (((size_t)b * NS + tile * SB + srow) * NH + h) * NE + c16);
    float4 a = p4[0], bq = p4[1], c = p4[2], d = p4[3];
    unsigned u0 = cvt_pk_bf16(a.x, a.y), u1 = cvt_pk_bf16(a.z, a.w);
    unsigned u2 = cvt_pk_bf16(bq.x, bq.y), u3 = cvt_pk_bf16(bq.z, bq.w);
    unsigned u4 = cvt_pk_bf16(c.x, c.y), u5 = cvt_pk_bf16(c.z, c.w);
    unsigned u6 = cvt_pk_bf16(d.x, d.y), u7 = cvt_pk_bf16(d.z, d.w);
    char* base = (char*)kimg + (size_t)blk * TILE_B;
    int off0 = (c16 >> 4) * 2048 + (srow >> 5) * 1024 + (srow & 31) * 16;
    uint4 w0 = {u0, u1, u2, u3}, w1 = {u4, u5, u6, u7};
    *(uint4*)(base + off0) = w0;
    *(uint4*)(base + off0 + 512) = w1;
  }
  {  // V: exp(V), transpose via LDS, fragment-ordered
    __shared__ short Vsh[64 * 72];   // [d][s], stride 72 shorts
    const float4* p4 =
        (const float4*)(Vg + (((size_t)b * NS + tile * SB + srow) * NH + h) * ND + c16);
    float4 va = p4[0], vb = p4[1], vc = p4[2], vd = p4[3];
    float fv[16] = {va.x, va.y, va.z, va.w, vb.x, vb.y, vb.z, vb.w,
                    vc.x, vc.y, vc.z, vc.w, vd.x, vd.y, vd.z, vd.w};
#pragma unroll
    for (int i = 0; i < 16; ++i)
      Vsh[(c16 + i) * 72 + srow] = f2bf(__expf(fv[i]));
    __syncthreads();
    int dr = t >> 2, sc = (t & 3) * 16;
    bf16x8 o0 = *(const bf16x8*)&Vsh[dr * 72 + sc];
    bf16x8 o1 = *(const bf16x8*)&Vsh[dr * 72 + sc + 8];
    char* base = (char*)vimg + (size_t)blk * TILE_B;
    int off0 = (sc >> 4) * 2048 + (dr >> 5) * 1024 + (dr & 31) * 16;
    *(bf16x8*)(base + off0) = o0;
    *(bf16x8*)(base + off0 + 512) = o1;
  }
}

// ---- main kernel: swapped-QK^T 32x32 MFMA, S-split x2, K+V LDS dbuf with
// counted-vmcnt raw-barrier pipeline (loads stay in flight across barriers) --
// Block = (b,h, 128 q-rows), 8 warps: grp0 tiles 0..31, grp1 tiles 32..63.
__global__ __launch_bounds__(512) void laser_fast(
    const float* __restrict__ Qg, const ushort_t* __restrict__ Kimg,
    const ushort_t* __restrict__ Vimg, float* __restrict__ Og) {
  int orig = blockIdx.x;
  int bid = (orig & 7) * 64 + (orig >> 3);   // bijective XCD swizzle (512%8==0)
  int qt = bid & 31;                         // 32 q-tiles of 128
  int bh = bid >> 5;
  int b = bh >> 3, hh = bh & 7;
  int t = threadIdx.x;
  int w = t >> 6;        // warp 0..7
  int grp = w >> 2;      // S-chunk group
  int wi = w & 3;        // q-subtile within block
  int lane = t & 63;
  int lq = lane & 31;    // q-col in QK^T, d-col in PV
  int h = lane >> 5;     // lane half

  __shared__ __attribute__((aligned(16))) char smem[65536];
  // K tiles: grp g, buf b -> smem + g*16384 + b*8192 ; V at +32768.
  char* kls = smem + grp * 16384;
  char* vls = smem + 32768 + grp * 16384;

  const char* kbase = (const char*)Kimg + (size_t)bh * (NT * TILE_B);
  const char* vbase = (const char*)Vimg + (size_t)bh * (NT * TILE_B);

  // Q' fragments: B-operand, lane holds Q'[q=lq][e = 16kk + 8h + j], pre-scaled
  int q0 = qt * 128 + wi * 32;
  const float* qp = Qg + (((size_t)b * NL + q0 + lq) * NH + hh) * NE;
  bf16x8 qf[4];
#pragma unroll
  for (int kk = 0; kk < 4; ++kk) {
    int e0 = 16 * kk + 8 * h;
    float4 x = *(const float4*)(qp + e0);
    float4 y = *(const float4*)(qp + e0 + 4);
    union { bf16x8 v; unsigned u[4]; } tm;
    tm.u[0] = cvt_pk_bf16(x.x * SC2, x.y * SC2);
    tm.u[1] = cvt_pk_bf16(x.z * SC2, x.w * SC2);
    tm.u[2] = cvt_pk_bf16(y.x * SC2, y.y * SC2);
    tm.u[3] = cvt_pk_bf16(y.z * SC2, y.w * SC2);
    qf[kk] = tm.v;
  }

  f32x16 acc0, acc1;
  float l_r = 0.f;
#pragma unroll
  for (int i = 0; i < 16; ++i) { acc0[i] = 0.f; acc1[i] = 0.f; }

  int soff = wi * 2048 + lane * 16;  // staging offset within tile image
  int tbase = grp * GT;              // group's first tile
  int fb = h * 512 + lq * 16;        // per-lane fragment base

#define STAGE(buf, ti)                                                       \
  do {                                                                       \
    const char* ks = kbase + (size_t)(tbase + (ti)) * TILE_B + soff;         \
    const char* vs = vbase + (size_t)(tbase + (ti)) * TILE_B + soff;         \
    gload16(ks, kls + (buf) * 8192 + wi * 2048);                             \
    gload16(ks + 1024, kls + (buf) * 8192 + wi * 2048 + 1024);               \
    gload16(vs, vls + (buf) * 8192 + wi * 2048);                             \
    gload16(vs + 1024, vls + (buf) * 8192 + wi * 2048 + 1024);               \
  } while (0)

#define MAKE_PA(P, g, idx)                                                   \
    do {                                                                     \
      unsigned a0 = cvt_pk_bf16(P[8 * (g) + 0], P[8 * (g) + 1]);             \
      unsigned a1 = cvt_pk_bf16(P[8 * (g) + 2], P[8 * (g) + 3]);             \
      unsigned b0 = cvt_pk_bf16(P[8 * (g) + 4], P[8 * (g) + 5]);             \
      unsigned b1 = cvt_pk_bf16(P[8 * (g) + 6], P[8 * (g) + 7]);             \
      auto w02 = __builtin_amdgcn_permlane32_swap(a0, b0, false, false);     \
      auto w13 = __builtin_amdgcn_permlane32_swap(a1, b1, false, false);     \
      union { bf16x8 v; unsigned u[4]; } tm;                                 \
      tm.u[0] = w02[0]; tm.u[1] = w13[0]; tm.u[2] = w02[1]; tm.u[3] = w13[1];\
      pa[idx] = tm.v;                                                        \
    } while (0)

#define COMPUTE(curb)                                                        \
  do {                                                                       \
    const char* Kc = kls + (curb) * 8192;                                    \
    const char* Vc = vls + (curb) * 8192;                                    \
    f32x16 s0, s1;                                                           \
    _Pragma("unroll")                                                        \
    for (int i = 0; i < 16; ++i) { s0[i] = 0.f; s1[i] = 0.f; }               \
    __builtin_amdgcn_s_setprio(1);                                           \
    _Pragma("unroll")                                                        \
    for (int kk = 0; kk < 4; ++kk) {                                         \
      bf16x8 ka = *(const bf16x8*)(Kc + fb + kk * 2048);                     \
      bf16x8 kb = *(const bf16x8*)(Kc + fb + kk * 2048 + 1024);              \
      s0 = __builtin_amdgcn_mfma_f32_32x32x16_bf16(ka, qf[kk], s0, 0, 0, 0); \
      s1 = __builtin_amdgcn_mfma_f32_32x32x16_bf16(kb, qf[kk], s1, 0, 0, 0); \
    }                                                                        \
    __builtin_amdgcn_s_setprio(0);                                           \
    _Pragma("unroll")                                                        \
    for (int i = 0; i < 16; ++i) {                                           \
      s0[i] = __builtin_amdgcn_exp2f(s0[i]);                                 \
      s1[i] = __builtin_amdgcn_exp2f(s1[i]);                                 \
    }                                                                        \
    {                                                                        \
      float t0 = (s0[0] + s0[1]) + (s0[2] + s0[3]);                          \
      float t1 = (s0[4] + s0[5]) + (s0[6] + s0[7]);                          \
      float t2 = (s0[8] + s0[9]) + (s0[10] + s0[11]);                        \
      float t3 = (s0[12] + s0[13]) + (s0[14] + s0[15]);                      \
      float t4 = (s1[0] + s1[1]) + (s1[2] + s1[3]);                          \
      float t5 = (s1[4] + s1[5]) + (s1[6] + s1[7]);                          \
      float t6 = (s1[8] + s1[9]) + (s1[10] + s1[11]);                        \
      float t7 = (s1[12] + s1[13]) + (s1[14] + s1[15]);                      \
      l_r += ((t0 + t1) + (t2 + t3)) + ((t4 + t5) + (t6 + t7));              \
    }                                                                        \
    bf16x8 pa[4];                                                            \
    MAKE_PA(s0, 0, 0);                                                       \
    MAKE_PA(s0, 1, 1);                                                       \
    MAKE_PA(s1, 0, 2);                                                       \
    MAKE_PA(s1, 1, 3);                                                       \
    __builtin_amdgcn_s_setprio(1);                                           \
    _Pragma("unroll")                                                        \
    for (int kk = 0; kk < 4; ++kk) {                                         \
      bf16x8 v0 = *(const bf16x8*)(Vc + fb + kk * 2048);                     \
      bf16x8 v1 = *(const bf16x8*)(Vc + fb + kk * 2048 + 1024);              \
      acc0 = __builtin_amdgcn_mfma_f32_32x32x16_bf16(pa[kk], v0, acc0, 0, 0, 0); \
      acc1 = __builtin_amdgcn_mfma_f32_32x32x16_bf16(pa[kk], v1, acc1, 0, 0, 0); \
    }                                                                        \
    __builtin_amdgcn_s_setprio(0);                                           \
  } while (0)

  // counted-vmcnt raw-barrier pipeline: loads stay in flight across barriers.
  STAGE(0, 0);
  int cur = 0;
  for (int ti = 0; ti < GT - 1; ++ti) {
    STAGE(cur ^ 1, ti + 1);                     // 8 loads now in flight
    asm volatile("s_waitcnt vmcnt(4)" ::: "memory");  // cur's 4 (oldest) done
    __builtin_amdgcn_s_barrier();               // cur tile complete block-wide
    COMPUTE(cur);
    asm volatile("s_waitcnt lgkmcnt(0)" ::: "memory"); // all reads of cur retired
    __builtin_amdgcn_s_barrier();               // safe to overwrite cur next iter
    cur ^= 1;
  }
  asm volatile("s_waitcnt vmcnt(0)" ::: "memory");
  __builtin_amdgcn_s_barrier();
  COMPUTE(cur);
#undef STAGE
#undef MAKE_PA
#undef COMPUTE

  // ---- combine the two S-chunk partials (plain sums) via LDS ----
  __syncthreads();   // all compute done; K/V buffers dead, reuse smem
  float* exch = (float*)(void*)smem;              // 4 wi * 32 vals * 64 lanes
  float* lex  = (float*)(void*)(smem + 32768);    // 4 wi * 64 lanes
  float* lsm  = (float*)(void*)(smem + 33792);    // 4 wi * 32 q
  if (grp == 1) {
    float* e = exch + wi * 2048 + lane;
#pragma unroll
    for (int r = 0; r < 16; ++r) {
      e[r * 64] = acc0[r];
      e[(16 + r) * 64] = acc1[r];
    }
    lex[wi * 64 + lane] = l_r;
  }
  __syncthreads();
  if (grp == 0) {
    float* e = exch + wi * 2048 + lane;
#pragma unroll
    for (int r = 0; r < 16; ++r) {
      acc0[r] += e[r * 64];
      acc1[r] += e[(16 + r) * 64];
    }
    l_r += lex[wi * 64 + lane];

    // merge l across lane halves: l_tot[q=lq] = l_r[lane] + l_r[lane^32]
    union { float f; unsigned u; } cu;
    cu.f = l_r;
    auto mm = __builtin_amdgcn_permlane32_swap(cu.u, cu.u, false, false);
    union { unsigned u; float f; } m0, m1;
    m0.u = mm[0]; m1.u = mm[1];
    lsm[wi * 32 + lq] = m0.f + m1.f;   // same-wave write; read below (same wave)

    // out = log(O) - log(l[q]) ; vmax cancels exactly in log domain.
#pragma unroll
    for (int r = 0; r < 16; ++r) {
      int q = (r & 3) + 8 * (r >> 2) + 4 * h;
      float logl = __logf(lsm[wi * 32 + q]);
      size_t o = (((size_t)b * NL + q0 + q) * NH + hh) * ND + lq;
      Og[o] = __logf(acc0[r]) - logl;
      Og[o + 32] = __logf(acc1[r]) - logl;
    }
  }
}

// ---- slow fallback path (self-contained, needs vmax) ----
__global__ void vmax_partial(const float* __restrict__ Vp, float* __restrict__ part) {
  int blk = blockIdx.x;
  int bh = blk >> 4, ck = blk & 15;
  int b = bh >> 3, h = bh & 7;
  int t = threadIdx.x;
  int d = t & 63, g = t >> 6;
  const float* base = Vp + (((size_t)b * NS + ck * 256) * NH + h) * ND + d;
  float m = -INFINITY;
  for (int s = g; s < 256; s += 4)
    m = fmaxf(m, base[(size_t)s * NH * ND]);
  __shared__ float red[4][64];
  red[g][d] = m;
  __syncthreads();
  if (t < 64)
    part[(size_t)blk * 64 + t] =
        fmaxf(fmaxf(red[0][t], red[1][t]), fmaxf(red[2][t], red[3][t]));
}

__global__ void vmax_reduce(const float* __restrict__ part, float* __restrict__ vmax) {
  int bh = blockIdx.x, t = threadIdx.x;
  float m = -INFINITY;
#pragma unroll
  for (int c = 0; c < 16; ++c)
    m = fmaxf(m, part[((size_t)bh * 16 + c) * 64 + t]);
  vmax[bh * 64 + t] = m;
}

__global__ __launch_bounds__(256) void laser_slow(
    const float* __restrict__ Qg, const float* __restrict__ Kg,
    const float* __restrict__ Vg, const float* __restrict__ vmax,
    float* __restrict__ Og) {
  int bid = blockIdx.x;
  int qt = bid & 63;
  int bh = bid >> 6;
  int b = bh >> 3, h = bh & 7;
  int t = threadIdx.x;
  int w = t >> 6;
  int lane = t & 63;
  int lr = lane & 15;
  int lg = lane >> 4;

  __shared__ short Kt[SB * NE];
  __shared__ short Vt[ND * SB];
  __shared__ short Pl[4][16 * SB];
  __shared__ float vmx[ND];

  if (t < ND) vmx[t] = vmax[bh * ND + t];

  int q0 = qt * 64;
  int qrow = q0 + w * 16 + lr;
  const float* qptr = Qg + (((size_t)b * NL + qrow) * NH + h) * NE;
  bf16x8 qf[2];
#pragma unroll
  for (int kf = 0; kf < 2; ++kf) {
    const float4* p4 = (const float4*)(qptr + kf * 32 + lg * 8);
    float4 a = p4[0], bq = p4[1];
    qf[kf][0] = f2bf(a.x);  qf[kf][1] = f2bf(a.y);
    qf[kf][2] = f2bf(a.z);  qf[kf][3] = f2bf(a.w);
    qf[kf][4] = f2bf(bq.x); qf[kf][5] = f2bf(bq.y);
    qf[kf][6] = f2bf(bq.z); qf[kf][7] = f2bf(bq.w);
  }

  f32x4 acc_o[4];
  float m_r[4], l_r[4];
  const f32x4 fzero = {0.f, 0.f, 0.f, 0.f};
#pragma unroll
  for (int i = 0; i < 4; ++i) { acc_o[i] = fzero; m_r[i] = -INFINITY; l_r[i] = 0.f; }

  const float scale = 0.125f;
  int srow = t >> 2;
  int c16 = (t & 3) * 16;

  for (int s0 = 0; s0 < NS; s0 += SB) {
    __syncthreads();
    {
      const float4* kp4 =
          (const float4*)(Kg + (((size_t)b * NS + (s0 + srow)) * NH + h) * NE + c16);
      float4 t0 = kp4[0], t1 = kp4[1], t2 = kp4[2], t3 = kp4[3];
      bf16x8 c0, c1;
      c0[0] = f2bf(t0.x); c0[1] = f2bf(t0.y); c0[2] = f2bf(t0.z); c0[3] = f2bf(t0.w);
      c0[4] = f2bf(t1.x); c0[5] = f2bf(t1.y); c0[6] = f2bf(t1.z); c0[7] = f2bf(t1.w);
      c1[0] = f2bf(t2.x); c1[1] = f2bf(t2.y); c1[2] = f2bf(t2.z); c1[3] = f2bf(t2.w);
      c1[4] = f2bf(t3.x); c1[5] = f2bf(t3.y); c1[6] = f2bf(t3.z); c1[7] = f2bf(t3.w);
      int base = srow * 128 + c16 * 2;
      int swz = (srow & 7) << 4;
      *(bf16x8*)((char*)Kt + ((base) ^ swz)) = c0;
      *(bf16x8*)((char*)Kt + ((base + 16) ^ swz)) = c1;
    }
    {
      const float4* vp4 =
          (const float4*)(Vg + (((size_t)b * NS + (s0 + srow)) * NH + h) * ND + c16);
      float4 t0 = vp4[0], t1 = vp4[1], t2 = vp4[2], t3 = vp4[3];
      float fv[16] = {t0.x, t0.y, t0.z, t0.w, t1.x, t1.y, t1.z, t1.w,
                      t2.x, t2.y, t2.z, t2.w, t3.x, t3.y, t3.z, t3.w};
#pragma unroll
      for (int i = 0; i < 16; ++i) {
        int d = c16 + i;
        int byte = (d * 128 + srow * 2) ^ ((d & 7) << 4);
        *(short*)((char*)Vt + byte) = f2bf(__expf(fv[i] - vmx[d]));
      }
    }
    __syncthreads();

    f32x4 sacc[4];
#pragma unroll
    for (int jt = 0; jt < 4; ++jt) sacc[jt] = fzero;
#pragma unroll
    for (int jt = 0; jt < 4; ++jt) {
      int srw = jt * 16 + lr;
      int rb = srw * 128;
      int swz = (srw & 7) << 4;
      bf16x8 kb0 = *(const bf16x8*)((const char*)Kt + ((rb + lg * 16) ^ swz));
      bf16x8 kb1 = *(const bf16x8*)((const char*)Kt + ((rb + 64 + lg * 16) ^ swz));
      sacc[jt] = __builtin_amdgcn_mfma_f32_16x16x32_bf16(qf[0], kb0, sacc[jt], 0, 0, 0);
      sacc[jt] = __builtin_amdgcn_mfma_f32_16x16x32_bf16(qf[1], kb1, sacc[jt], 0, 0, 0);
    }

    float mnew[4], corr[4];
#pragma unroll
    for (int r = 0; r < 4; ++r) {
      float x = fmaxf(fmaxf(sacc[0][r], sacc[1][r]),
                      fmaxf(sacc[2][r], sacc[3][r])) * scale;
      x = fmaxf(x, __shfl_xor(x, 1));
      x = fmaxf(x, __shfl_xor(x, 2));
      x = fmaxf(x, __shfl_xor(x, 4));
      x = fmaxf(x, __shfl_xor(x, 8));
      mnew[r] = fmaxf(m_r[r], x);
      corr[r] = __expf(m_r[r] - mnew[r]);
    }
    float rs[4] = {0.f, 0.f, 0.f, 0.f};
    short pb[4][4];
#pragma unroll
    for (int jt = 0; jt < 4; ++jt)
#pragma unroll
      for (int r = 0; r < 4; ++r) {
        float p = __expf(sacc[jt][r] * scale - mnew[r]);
        rs[r] += p;
        pb[jt][r] = f2bf(p);
      }
#pragma unroll
    for (int r = 0; r < 4; ++r) {
      float x = rs[r];
      x += __shfl_xor(x, 1);
      x += __shfl_xor(x, 2);
      x += __shfl_xor(x, 4);
      x += __shfl_xor(x, 8);
      l_r[r] = l_r[r] * corr[r] + x;
      m_r[r] = mnew[r];
    }
    short* pwv = &Pl[w][0];
#pragma unroll
    for (int jt = 0; jt < 4; ++jt)
#pragma unroll
      for (int r = 0; r < 4; ++r) {
        int row = lg * 4 + r, col = jt * 16 + lr;
        int byte = (row * 128 + col * 2) ^ ((row & 7) << 4);
        *(short*)((char*)pwv + byte) = pb[jt][r];
      }
#pragma unroll
    for (int dt = 0; dt < 4; ++dt)
#pragma unroll
      for (int r = 0; r < 4; ++r) acc_o[dt][r] *= corr[r];
#pragma unroll
    for (int kf = 0; kf < 2; ++kf) {
      int ab = lr * 128;
      int aswz = (lr & 7) << 4;
      bf16x8 pa = *(const bf16x8*)((const char*)pwv + ((ab + kf * 64 + lg * 16) ^ aswz));
#pragma unroll
      for (int dt = 0; dt < 4; ++dt) {
        int drow = dt * 16 + lr;
        int vb_byte = (drow * 128 + kf * 64 + lg * 16) ^ ((drow & 7) << 4);
        bf16x8 vb = *(const bf16x8*)((const char*)Vt + vb_byte);
        acc_o[dt] = __builtin_amdgcn_mfma_f32_16x16x32_bf16(pa, vb, acc_o[dt], 0, 0, 0);
      }
    }
  }

#pragma unroll
  for (int r = 0; r < 4; ++r) {
    int row = q0 + w * 16 + lg * 4 + r;
    float logl = __logf(l_r[r]);
#pragma unroll
    for (int dt = 0; dt < 4; ++dt) {
      int d = dt * 16 + lr;
      Og[(((size_t)b * NL + row) * NH + h) * ND + d] =
          __logf(acc_o[dt][r]) - logl + vmx[d];
    }
  }
}

extern "C" void kernel_launch(void* const* d_in, const int* in_sizes, int n_in,
                              void* d_out, int out_size, void* d_ws, size_t ws_size,
                              hipStream_t stream) {
  (void)in_sizes; (void)n_in; (void)out_size;
  const float* Q = (const float*)d_in[0];
  const float* K = (const float*)d_in[1];
  const float* V = (const float*)d_in[2];
  float* out = (float*)d_out;

  float* vmax = (float*)d_ws;                         // 4KB (slow path only)
  float* part = (float*)((char*)d_ws + 4096);         // 64KB (slow path only)
  const size_t kimg_off = 1u << 20;                   // 1MB
  const size_t vimg_off = (size_t)9u << 20;           // 9MB
  const size_t img_bytes = (size_t)16 * NT * TILE_B;  // 8MB each
  bool fast = ws_size >= vimg_off + img_bytes;

  if (fast) {
    ushort_t* kimg = (ushort_t*)((char*)d_ws + kimg_off);
    ushort_t* vimg = (ushort_t*)((char*)d_ws + vimg_off);
    kvprep<<<dim3(1024), dim3(256), 0, stream>>>(K, V, kimg, vimg);
    laser_fast<<<dim3(512), dim3(512), 0, stream>>>(Q, kimg, vimg, out);
  } else {
    vmax_partial<<<dim3(256), dim3(256), 0, stream>>>(V, part);
    vmax_reduce<<<dim3(16), dim3(64), 0, stream>>>(part, vmax);
    laser_slow<<<dim3(1024), dim3(256), 0, stream>>>(Q, K, V, vmax, out);
  }
}

// Round 18
// 91.567 us; speedup vs baseline: 1.0443x; 1.0122x over previous
//
#include <hip/hip_runtime.h>
#include <math.h>

#define NB 2
#define NL 4096
#define NS 4096
#define NH 8
#define NE 64
#define ND 64
#define SB 64
#define NT (NS / SB)
#define GT (NT / 2)            // tiles per warp-group (S split in 2)
#define TILE_B 8192            // one 64x64 bf16 tile image, bytes
#define LOG2E 1.4426950408889634f
#define SC2 (0.125f * LOG2E)   // scale * log2(e), folded into Q

typedef __attribute__((ext_vector_type(8))) short bf16x8;
typedef __attribute__((ext_vector_type(4))) float f32x4;
typedef __attribute__((ext_vector_type(16))) float f32x16;
typedef unsigned short ushort_t;

__device__ __forceinline__ short f2bf(float f) {
  union { float f; unsigned u; } v; v.f = f;
  unsigned u = v.u;
  return (short)((u + 0x7fffu + ((u >> 16) & 1u)) >> 16);
}

__device__ __forceinline__ unsigned cvt_pk_bf16(float lo, float hi) {
  unsigned r;
  asm("v_cvt_pk_bf16_f32 %0, %1, %2" : "=v"(r) : "v"(lo), "v"(hi));
  return r;
}

__device__ __forceinline__ void gload16(const void* g, void* l) {
  __builtin_amdgcn_global_load_lds(
      (const __attribute__((address_space(1))) void*)g,
      (__attribute__((address_space(3))) void*)l, 16, 0, 0);
}

// Fragment-ordered tile image layout (both K and V^T tiles):
//   byte_off(kk, j, h, lq) = kk*2048 + j*1024 + h*512 + lq*16
// A wave's fragment read (kk,j) covers 1024 contiguous bytes -> conflict-free.

// ---- fused prep: K -> bf16 images ; V -> exp(V) (no vmax: cancels in the
// log-domain epilogue), transposed [d][s], fragment-ordered images ----
__global__ __launch_bounds__(256) void kvprep(const float* __restrict__ Kg,
                                              const float* __restrict__ Vg,
                                              ushort_t* __restrict__ kimg,
                                              ushort_t* __restrict__ vimg) {
  int blk = blockIdx.x;              // 1024 = bh*64 + tile
  int bh = blk >> 6, tile = blk & 63;
  int b = bh >> 3, h = bh & 7;
  int t = threadIdx.x;
  int srow = t >> 2, c16 = (t & 3) * 16;
  {  // K
    const float4* p4 =
        (const float4*)(Kg + (((size_t)b * NS + tile * SB + srow) * NH + h) * NE + c16);
    float4 a = p4[0], bq = p4[1], c = p4[2], d = p4[3];
    unsigned u0 = cvt_pk_bf16(a.x, a.y), u1 = cvt_pk_bf16(a.z, a.w);
    unsigned u2 = cvt_pk_bf16(bq.x, bq.y), u3 = cvt_pk_bf16(bq.z, bq.w);
    unsigned u4 = cvt_pk_bf16(c.x, c.y), u5 = cvt_pk_bf16(c.z, c.w);
    unsigned u6 = cvt_pk_bf16(d.x, d.y), u7 = cvt_pk_bf16(d.z, d.w);
    char* base = (char*)kimg + (size_t)blk * TILE_B;
    int off0 = (c16 >> 4) * 2048 + (srow >> 5) * 1024 + (srow & 31) * 16;
    uint4 w0 = {u0, u1, u2, u3}, w1 = {u4, u5, u6, u7};
    *(uint4*)(base + off0) = w0;
    *(uint4*)(base + off0 + 512) = w1;
  }
  {  // V: exp(V), transpose via LDS, fragment-ordered
    __shared__ short Vsh[64 * 72];   // [d][s], stride 72 shorts
    const float4* p4 =
        (const float4*)(Vg + (((size_t)b * NS + tile * SB + srow) * NH + h) * ND + c16);
    float4 va = p4[0], vb = p4[1], vc = p4[2], vd = p4[3];
    float fv[16] = {va.x, va.y, va.z, va.w, vb.x, vb.y, vb.z, vb.w,
                    vc.x, vc.y, vc.z, vc.w, vd.x, vd.y, vd.z, vd.w};
#pragma unroll
    for (int i = 0; i < 16; ++i)
      Vsh[(c16 + i) * 72 + srow] = f2bf(__expf(fv[i]));
    __syncthreads();
    int dr = t >> 2, sc = (t & 3) * 16;
    bf16x8 o0 = *(const bf16x8*)&Vsh[dr * 72 + sc];
    bf16x8 o1 = *(const bf16x8*)&Vsh[dr * 72 + sc + 8];
    char* base = (char*)vimg + (size_t)blk * TILE_B;
    int off0 = (sc >> 4) * 2048 + (dr >> 5) * 1024 + (dr & 31) * 16;
    *(bf16x8*)(base + off0) = o0;
    *(bf16x8*)(base + off0 + 512) = o1;
  }
}

// ---- main kernel: swapped-QK^T 32x32 MFMA, S-split x2, 64 q-rows/wave
// (two subtiles, K-frags register-cached -> halved K LDS reads), K+V LDS
// dbuf with counted-vmcnt raw-barrier pipeline ----
// Block = (b,h, 256 q-rows), 8 warps: grp0 tiles 0..31, grp1 tiles 32..63.
__global__ __launch_bounds__(512, 2) void laser_fast(
    const float* __restrict__ Qg, const ushort_t* __restrict__ Kimg,
    const ushort_t* __restrict__ Vimg, float* __restrict__ Og) {
  int orig = blockIdx.x;
  int bid = (orig & 7) * 32 + (orig >> 3);   // bijective XCD swizzle (256%8==0)
  int qt = bid & 15;                         // 16 q-tiles of 256
  int bh = bid >> 4;
  int b = bh >> 3, hh = bh & 7;
  int t = threadIdx.x;
  int w = t >> 6;        // warp 0..7
  int grp = w >> 2;      // S-chunk group
  int wi = w & 3;        // q-subtile-pair within block
  int lane = t & 63;
  int lq = lane & 31;    // q-col in QK^T, d-col in PV
  int h = lane >> 5;     // lane half

  // Loop phase uses [0,64K): K grp g buf b at g*16384+b*8192; V at +32768.
  // Epilogue: exch 64KB @0, lex 2KB @65536, lsm 1KB @67584.
  __shared__ __attribute__((aligned(16))) char smem[68608];
  char* kls = smem + grp * 16384;
  char* vls = smem + 32768 + grp * 16384;

  const char* kbase = (const char*)Kimg + (size_t)bh * (NT * TILE_B);
  const char* vbase = (const char*)Vimg + (size_t)bh * (NT * TILE_B);

  // Q' fragments for both subtiles (rows q0+lq and q0+32+lq), pre-scaled
  int q0 = qt * 256 + wi * 64;
  const float* qpa = Qg + (((size_t)b * NL + q0 + lq) * NH + hh) * NE;
  const float* qpb = Qg + (((size_t)b * NL + q0 + 32 + lq) * NH + hh) * NE;
  bf16x8 qfa[4], qfb[4];
#pragma unroll
  for (int kk = 0; kk < 4; ++kk) {
    int e0 = 16 * kk + 8 * h;
    float4 x = *(const float4*)(qpa + e0);
    float4 y = *(const float4*)(qpa + e0 + 4);
    union { bf16x8 v; unsigned u[4]; } tm;
    tm.u[0] = cvt_pk_bf16(x.x * SC2, x.y * SC2);
    tm.u[1] = cvt_pk_bf16(x.z * SC2, x.w * SC2);
    tm.u[2] = cvt_pk_bf16(y.x * SC2, y.y * SC2);
    tm.u[3] = cvt_pk_bf16(y.z * SC2, y.w * SC2);
    qfa[kk] = tm.v;
    float4 x2 = *(const float4*)(qpb + e0);
    float4 y2 = *(const float4*)(qpb + e0 + 4);
    tm.u[0] = cvt_pk_bf16(x2.x * SC2, x2.y * SC2);
    tm.u[1] = cvt_pk_bf16(x2.z * SC2, x2.w * SC2);
    tm.u[2] = cvt_pk_bf16(y2.x * SC2, y2.y * SC2);
    tm.u[3] = cvt_pk_bf16(y2.z * SC2, y2.w * SC2);
    qfb[kk] = tm.v;
  }

  f32x16 acca0, acca1, accb0, accb1;
  float l_a = 0.f, l_b = 0.f;
#pragma unroll
  for (int i = 0; i < 16; ++i) {
    acca0[i] = 0.f; acca1[i] = 0.f; accb0[i] = 0.f; accb1[i] = 0.f;
  }

  int soff = wi * 2048 + lane * 16;  // staging offset within tile image
  int tbase = grp * GT;              // group's first tile
  int fb = h * 512 + lq * 16;        // per-lane fragment base

#define STAGE(buf, ti)                                                       \
  do {                                                                       \
    const char* ks = kbase + (size_t)(tbase + (ti)) * TILE_B + soff;         \
    const char* vs = vbase + (size_t)(tbase + (ti)) * TILE_B + soff;         \
    gload16(ks, kls + (buf) * 8192 + wi * 2048);                             \
    gload16(ks + 1024, kls + (buf) * 8192 + wi * 2048 + 1024);               \
    gload16(vs, vls + (buf) * 8192 + wi * 2048);                             \
    gload16(vs + 1024, vls + (buf) * 8192 + wi * 2048 + 1024);               \
  } while (0)

#define MAKE_PA(P0, P1)                                                      \
    do {                                                                     \
      unsigned a0, a1, b0, b1;                                               \
      a0 = cvt_pk_bf16(P0[0], P0[1]); a1 = cvt_pk_bf16(P0[2], P0[3]);        \
      b0 = cvt_pk_bf16(P0[4], P0[5]); b1 = cvt_pk_bf16(P0[6], P0[7]);        \
      {                                                                      \
        auto w02 = __builtin_amdgcn_permlane32_swap(a0, b0, false, false);   \
        auto w13 = __builtin_amdgcn_permlane32_swap(a1, b1, false, false);   \
        union { bf16x8 v; unsigned u[4]; } tm;                               \
        tm.u[0] = w02[0]; tm.u[1] = w13[0]; tm.u[2] = w02[1]; tm.u[3] = w13[1]; \
        pa[0] = tm.v;                                                        \
      }                                                                      \
      a0 = cvt_pk_bf16(P0[8], P0[9]);   a1 = cvt_pk_bf16(P0[10], P0[11]);    \
      b0 = cvt_pk_bf16(P0[12], P0[13]); b1 = cvt_pk_bf16(P0[14], P0[15]);    \
      {                                                                      \
        auto w02 = __builtin_amdgcn_permlane32_swap(a0, b0, false, false);   \
        auto w13 = __builtin_amdgcn_permlane32_swap(a1, b1, false, false);   \
        union { bf16x8 v; unsigned u[4]; } tm;                               \
        tm.u[0] = w02[0]; tm.u[1] = w13[0]; tm.u[2] = w02[1]; tm.u[3] = w13[1]; \
        pa[1] = tm.v;                                                        \
      }                                                                      \
      a0 = cvt_pk_bf16(P1[0], P1[1]); a1 = cvt_pk_bf16(P1[2], P1[3]);        \
      b0 = cvt_pk_bf16(P1[4], P1[5]); b1 = cvt_pk_bf16(P1[6], P1[7]);        \
      {                                                                      \
        auto w02 = __builtin_amdgcn_permlane32_swap(a0, b0, false, false);   \
        auto w13 = __builtin_amdgcn_permlane32_swap(a1, b1, false, false);   \
        union { bf16x8 v; unsigned u[4]; } tm;                               \
        tm.u[0] = w02[0]; tm.u[1] = w13[0]; tm.u[2] = w02[1]; tm.u[3] = w13[1]; \
        pa[2] = tm.v;                                                        \
      }                                                                      \
      a0 = cvt_pk_bf16(P1[8], P1[9]);   a1 = cvt_pk_bf16(P1[10], P1[11]);    \
      b0 = cvt_pk_bf16(P1[12], P1[13]); b1 = cvt_pk_bf16(P1[14], P1[15]);    \
      {                                                                      \
        auto w02 = __builtin_amdgcn_permlane32_swap(a0, b0, false, false);   \
        auto w13 = __builtin_amdgcn_permlane32_swap(a1, b1, false, false);   \
        union { bf16x8 v; unsigned u[4]; } tm;                               \
        tm.u[0] = w02[0]; tm.u[1] = w13[0]; tm.u[2] = w02[1]; tm.u[3] = w13[1]; \
        pa[3] = tm.v;                                                        \
      }                                                                      \
    } while (0)

#define SUMTREE(dst, P0, P1)                                                 \
    do {                                                                     \
      float t0 = (P0[0] + P0[1]) + (P0[2] + P0[3]);                          \
      float t1 = (P0[4] + P0[5]) + (P0[6] + P0[7]);                          \
      float t2 = (P0[8] + P0[9]) + (P0[10] + P0[11]);                        \
      float t3 = (P0[12] + P0[13]) + (P0[14] + P0[15]);                      \
      float t4 = (P1[0] + P1[1]) + (P1[2] + P1[3]);                          \
      float t5 = (P1[4] + P1[5]) + (P1[6] + P1[7]);                          \
      float t6 = (P1[8] + P1[9]) + (P1[10] + P1[11]);                        \
      float t7 = (P1[12] + P1[13]) + (P1[14] + P1[15]);                      \
      dst += ((t0 + t1) + (t2 + t3)) + ((t4 + t5) + (t6 + t7));              \
    } while (0)

#define COMPUTE(curb)                                                        \
  do {                                                                       \
    const char* Kc = kls + (curb) * 8192;                                    \
    const char* Vc = vls + (curb) * 8192;                                    \
    bf16x8 kf[8];                                                            \
    _Pragma("unroll")                                                        \
    for (int kk = 0; kk < 4; ++kk) {                                         \
      kf[2 * kk] = *(const bf16x8*)(Kc + fb + kk * 2048);                    \
      kf[2 * kk + 1] = *(const bf16x8*)(Kc + fb + kk * 2048 + 1024);         \
    }                                                                        \
    f32x16 s0, s1, u0, u1;                                                   \
    _Pragma("unroll")                                                        \
    for (int i = 0; i < 16; ++i) { s0[i] = 0.f; s1[i] = 0.f; u0[i] = 0.f; u1[i] = 0.f; } \
    __builtin_amdgcn_s_setprio(1);                                           \
    _Pragma("unroll")                                                        \
    for (int kk = 0; kk < 4; ++kk) {                                         \
      s0 = __builtin_amdgcn_mfma_f32_32x32x16_bf16(kf[2 * kk], qfa[kk], s0, 0, 0, 0); \
      s1 = __builtin_amdgcn_mfma_f32_32x32x16_bf16(kf[2 * kk + 1], qfa[kk], s1, 0, 0, 0); \
    }                                                                        \
    _Pragma("unroll")                                                        \
    for (int kk = 0; kk < 4; ++kk) {                                         \
      u0 = __builtin_amdgcn_mfma_f32_32x32x16_bf16(kf[2 * kk], qfb[kk], u0, 0, 0, 0); \
      u1 = __builtin_amdgcn_mfma_f32_32x32x16_bf16(kf[2 * kk + 1], qfb[kk], u1, 0, 0, 0); \
    }                                                                        \
    __builtin_amdgcn_s_setprio(0);                                           \
    _Pragma("unroll")                                                        \
    for (int i = 0; i < 16; ++i) {                                           \
      s0[i] = __builtin_amdgcn_exp2f(s0[i]);                                 \
      s1[i] = __builtin_amdgcn_exp2f(s1[i]);                                 \
    }                                                                        \
    SUMTREE(l_a, s0, s1);                                                    \
    {                                                                        \
      bf16x8 pa[4];                                                          \
      MAKE_PA(s0, s1);                                                       \
      __builtin_amdgcn_s_setprio(1);                                         \
      _Pragma("unroll")                                                      \
      for (int kk = 0; kk < 4; ++kk) {                                       \
        bf16x8 v0 = *(const bf16x8*)(Vc + fb + kk * 2048);                   \
        bf16x8 v1 = *(const bf16x8*)(Vc + fb + kk * 2048 + 1024);            \
        acca0 = __builtin_amdgcn_mfma_f32_32x32x16_bf16(pa[kk], v0, acca0, 0, 0, 0); \
        acca1 = __builtin_amdgcn_mfma_f32_32x32x16_bf16(pa[kk], v1, acca1, 0, 0, 0); \
      }                                                                      \
      __builtin_amdgcn_s_setprio(0);                                         \
    }                                                                        \
    _Pragma("unroll")                                                        \
    for (int i = 0; i < 16; ++i) {                                           \
      u0[i] = __builtin_amdgcn_exp2f(u0[i]);                                 \
      u1[i] = __builtin_amdgcn_exp2f(u1[i]);                                 \
    }                                                                        \
    SUMTREE(l_b, u0, u1);                                                    \
    {                                                                        \
      bf16x8 pa[4];                                                          \
      MAKE_PA(u0, u1);                                                       \
      __builtin_amdgcn_s_setprio(1);                                         \
      _Pragma("unroll")                                                      \
      for (int kk = 0; kk < 4; ++kk) {                                       \
        bf16x8 v0 = *(const bf16x8*)(Vc + fb + kk * 2048);                   \
        bf16x8 v1 = *(const bf16x8*)(Vc + fb + kk * 2048 + 1024);            \
        accb0 = __builtin_amdgcn_mfma_f32_32x32x16_bf16(pa[kk], v0, accb0, 0, 0, 0); \
        accb1 = __builtin_amdgcn_mfma_f32_32x32x16_bf16(pa[kk], v1, accb1, 0, 0, 0); \
      }                                                                      \
      __builtin_amdgcn_s_setprio(0);                                         \
    }                                                                        \
  } while (0)

  // counted-vmcnt raw-barrier pipeline (r17): loads in flight across barriers
  STAGE(0, 0);
  int cur = 0;
  for (int ti = 0; ti < GT - 1; ++ti) {
    STAGE(cur ^ 1, ti + 1);
    asm volatile("s_waitcnt vmcnt(4)" ::: "memory");
    __builtin_amdgcn_s_barrier();
    COMPUTE(cur);
    asm volatile("s_waitcnt lgkmcnt(0)" ::: "memory");
    __builtin_amdgcn_s_barrier();
    cur ^= 1;
  }
  asm volatile("s_waitcnt vmcnt(0)" ::: "memory");
  __builtin_amdgcn_s_barrier();
  COMPUTE(cur);
#undef STAGE
#undef MAKE_PA
#undef SUMTREE
#undef COMPUTE

  // ---- combine the two S-chunk partials (plain sums) via LDS ----
  __syncthreads();   // all compute done; staging buffers dead, reuse smem
  float* exch = (float*)(void*)smem;              // wi*4096 + r*64 + lane
  float* lex  = (float*)(void*)(smem + 65536);    // [4wi][2][64]
  float* lsm  = (float*)(void*)(smem + 67584);    // [4wi][2][32]
  if (grp == 1) {
    float* e = exch + wi * 4096 + lane;
#pragma unroll
    for (int r = 0; r < 16; ++r) {
      e[r * 64] = acca0[r];
      e[(16 + r) * 64] = acca1[r];
      e[(32 + r) * 64] = accb0[r];
      e[(48 + r) * 64] = accb1[r];
    }
    lex[wi * 128 + lane] = l_a;
    lex[wi * 128 + 64 + lane] = l_b;
  }
  __syncthreads();
  if (grp == 0) {
    float* e = exch + wi * 4096 + lane;
#pragma unroll
    for (int r = 0; r < 16; ++r) {
      acca0[r] += e[r * 64];
      acca1[r] += e[(16 + r) * 64];
      accb0[r] += e[(32 + r) * 64];
      accb1[r] += e[(48 + r) * 64];
    }
    l_a += lex[wi * 128 + lane];
    l_b += lex[wi * 128 + 64 + lane];

    // merge l across lane halves, redistribute by accumulator row via LDS
    union { float f; unsigned u; } cu;
    cu.f = l_a;
    auto ma = __builtin_amdgcn_permlane32_swap(cu.u, cu.u, false, false);
    union { unsigned u; float f; } x0, x1;
    x0.u = ma[0]; x1.u = ma[1];
    lsm[wi * 64 + lq] = x0.f + x1.f;
    cu.f = l_b;
    auto mb = __builtin_amdgcn_permlane32_swap(cu.u, cu.u, false, false);
    x0.u = mb[0]; x1.u = mb[1];
    lsm[wi * 64 + 32 + lq] = x0.f + x1.f;

    // out = log(O) - log(l[q]) ; vmax cancels exactly in log domain.
#pragma unroll
    for (int r = 0; r < 16; ++r) {
      int cr = (r & 3) + 8 * (r >> 2) + 4 * h;
      float logla = __logf(lsm[wi * 64 + cr]);
      float loglb = __logf(lsm[wi * 64 + 32 + cr]);
      size_t oa = (((size_t)b * NL + q0 + cr) * NH + hh) * ND + lq;
      size_t ob = (((size_t)b * NL + q0 + 32 + cr) * NH + hh) * ND + lq;
      Og[oa] = __logf(acca0[r]) - logla;
      Og[oa + 32] = __logf(acca1[r]) - logla;
      Og[ob] = __logf(accb0[r]) - loglb;
      Og[ob + 32] = __logf(accb1[r]) - loglb;
    }
  }
}

// ---- slow fallback path (self-contained, needs vmax) ----
__global__ void vmax_partial(const float* __restrict__ Vp, float* __restrict__ part) {
  int blk = blockIdx.x;
  int bh = blk >> 4, ck = blk & 15;
  int b = bh >> 3, h = bh & 7;
  int t = threadIdx.x;
  int d = t & 63, g = t >> 6;
  const float* base = Vp + (((size_t)b * NS + ck * 256) * NH + h) * ND + d;
  float m = -INFINITY;
  for (int s = g; s < 256; s += 4)
    m = fmaxf(m, base[(size_t)s * NH * ND]);
  __shared__ float red[4][64];
  red[g][d] = m;
  __syncthreads();
  if (t < 64)
    part[(size_t)blk * 64 + t] =
        fmaxf(fmaxf(red[0][t], red[1][t]), fmaxf(red[2][t], red[3][t]));
}

__global__ void vmax_reduce(const float* __restrict__ part, float* __restrict__ vmax) {
  int bh = blockIdx.x, t = threadIdx.x;
  float m = -INFINITY;
#pragma unroll
  for (int c = 0; c < 16; ++c)
    m = fmaxf(m, part[((size_t)bh * 16 + c) * 64 + t]);
  vmax[bh * 64 + t] = m;
}

__global__ __launch_bounds__(256) void laser_slow(
    const float* __restrict__ Qg, const float* __restrict__ Kg,
    const float* __restrict__ Vg, const float* __restrict__ vmax,
    float* __restrict__ Og) {
  int bid = blockIdx.x;
  int qt = bid & 63;
  int bh = bid >> 6;
  int b = bh >> 3, h = bh & 7;
  int t = threadIdx.x;
  int w = t >> 6;
  int lane = t & 63;
  int lr = lane & 15;
  int lg = lane >> 4;

  __shared__ short Kt[SB * NE];
  __shared__ short Vt[ND * SB];
  __shared__ short Pl[4][16 * SB];
  __shared__ float vmx[ND];

  if (t < ND) vmx[t] = vmax[bh * ND + t];

  int q0 = qt * 64;
  int qrow = q0 + w * 16 + lr;
  const float* qptr = Qg + (((size_t)b * NL + qrow) * NH + h) * NE;
  bf16x8 qf[2];
#pragma unroll
  for (int kf = 0; kf < 2; ++kf) {
    const float4* p4 = (const float4*)(qptr + kf * 32 + lg * 8);
    float4 a = p4[0], bq = p4[1];
    qf[kf][0] = f2bf(a.x);  qf[kf][1] = f2bf(a.y);
    qf[kf][2] = f2bf(a.z);  qf[kf][3] = f2bf(a.w);
    qf[kf][4] = f2bf(bq.x); qf[kf][5] = f2bf(bq.y);
    qf[kf][6] = f2bf(bq.z); qf[kf][7] = f2bf(bq.w);
  }

  f32x4 acc_o[4];
  float m_r[4], l_r[4];
  const f32x4 fzero = {0.f, 0.f, 0.f, 0.f};
#pragma unroll
  for (int i = 0; i < 4; ++i) { acc_o[i] = fzero; m_r[i] = -INFINITY; l_r[i] = 0.f; }

  const float scale = 0.125f;
  int srow = t >> 2;
  int c16 = (t & 3) * 16;

  for (int s0 = 0; s0 < NS; s0 += SB) {
    __syncthreads();
    {
      const float4* kp4 =
          (const float4*)(Kg + (((size_t)b * NS + (s0 + srow)) * NH + h) * NE + c16);
      float4 t0 = kp4[0], t1 = kp4[1], t2 = kp4[2], t3 = kp4[3];
      bf16x8 c0, c1;
      c0[0] = f2bf(t0.x); c0[1] = f2bf(t0.y); c0[2] = f2bf(t0.z); c0[3] = f2bf(t0.w);
      c0[4] = f2bf(t1.x); c0[5] = f2bf(t1.y); c0[6] = f2bf(t1.z); c0[7] = f2bf(t1.w);
      c1[0] = f2bf(t2.x); c1[1] = f2bf(t2.y); c1[2] = f2bf(t2.z); c1[3] = f2bf(t2.w);
      c1[4] = f2bf(t3.x); c1[5] = f2bf(t3.y); c1[6] = f2bf(t3.z); c1[7] = f2bf(t3.w);
      int base = srow * 128 + c16 * 2;
      int swz = (srow & 7) << 4;
      *(bf16x8*)((char*)Kt + ((base) ^ swz)) = c0;
      *(bf16x8*)((char*)Kt + ((base + 16) ^ swz)) = c1;
    }
    {
      const float4* vp4 =
          (const float4*)(Vg + (((size_t)b * NS + (s0 + srow)) * NH + h) * ND + c16);
      float4 t0 = vp4[0], t1 = vp4[1], t2 = vp4[2], t3 = vp4[3];
      float fv[16] = {t0.x, t0.y, t0.z, t0.w, t1.x, t1.y, t1.z, t1.w,
                      t2.x, t2.y, t2.z, t2.w, t3.x, t3.y, t3.z, t3.w};
#pragma unroll
      for (int i = 0; i < 16; ++i) {
        int d = c16 + i;
        int byte = (d * 128 + srow * 2) ^ ((d & 7) << 4);
        *(short*)((char*)Vt + byte) = f2bf(__expf(fv[i] - vmx[d]));
      }
    }
    __syncthreads();

    f32x4 sacc[4];
#pragma unroll
    for (int jt = 0; jt < 4; ++jt) sacc[jt] = fzero;
#pragma unroll
    for (int jt = 0; jt < 4; ++jt) {
      int srw = jt * 16 + lr;
      int rb = srw * 128;
      int swz = (srw & 7) << 4;
      bf16x8 kb0 = *(const bf16x8*)((const char*)Kt + ((rb + lg * 16) ^ swz));
      bf16x8 kb1 = *(const bf16x8*)((const char*)Kt + ((rb + 64 + lg * 16) ^ swz));
      sacc[jt] = __builtin_amdgcn_mfma_f32_16x16x32_bf16(qf[0], kb0, sacc[jt], 0, 0, 0);
      sacc[jt] = __builtin_amdgcn_mfma_f32_16x16x32_bf16(qf[1], kb1, sacc[jt], 0, 0, 0);
    }

    float mnew[4], corr[4];
#pragma unroll
    for (int r = 0; r < 4; ++r) {
      float x = fmaxf(fmaxf(sacc[0][r], sacc[1][r]),
                      fmaxf(sacc[2][r], sacc[3][r])) * scale;
      x = fmaxf(x, __shfl_xor(x, 1));
      x = fmaxf(x, __shfl_xor(x, 2));
      x = fmaxf(x, __shfl_xor(x, 4));
      x = fmaxf(x, __shfl_xor(x, 8));
      mnew[r] = fmaxf(m_r[r], x);
      corr[r] = __expf(m_r[r] - mnew[r]);
    }
    float rs[4] = {0.f, 0.f, 0.f, 0.f};
    short pb[4][4];
#pragma unroll
    for (int jt = 0; jt < 4; ++jt)
#pragma unroll
      for (int r = 0; r < 4; ++r) {
        float p = __expf(sacc[jt][r] * scale - mnew[r]);
        rs[r] += p;
        pb[jt][r] = f2bf(p);
      }
#pragma unroll
    for (int r = 0; r < 4; ++r) {
      float x = rs[r];
      x += __shfl_xor(x, 1);
      x += __shfl_xor(x, 2);
      x += __shfl_xor(x, 4);
      x += __shfl_xor(x, 8);
      l_r[r] = l_r[r] * corr[r] + x;
      m_r[r] = mnew[r];
    }
    short* pwv = &Pl[w][0];
#pragma unroll
    for (int jt = 0; jt < 4; ++jt)
#pragma unroll
      for (int r = 0; r < 4; ++r) {
        int row = lg * 4 + r, col = jt * 16 + lr;
        int byte = (row * 128 + col * 2) ^ ((row & 7) << 4);
        *(short*)((char*)pwv + byte) = pb[jt][r];
      }
#pragma unroll
    for (int dt = 0; dt < 4; ++dt)
#pragma unroll
      for (int r = 0; r < 4; ++r) acc_o[dt][r] *= corr[r];
#pragma unroll
    for (int kf = 0; kf < 2; ++kf) {
      int ab = lr * 128;
      int aswz = (lr & 7) << 4;
      bf16x8 pa = *(const bf16x8*)((const char*)pwv + ((ab + kf * 64 + lg * 16) ^ aswz));
#pragma unroll
      for (int dt = 0; dt < 4; ++dt) {
        int drow = dt * 16 + lr;
        int vb_byte = (drow * 128 + kf * 64 + lg * 16) ^ ((drow & 7) << 4);
        bf16x8 vb = *(const bf16x8*)((const char*)Vt + vb_byte);
        acc_o[dt] = __builtin_amdgcn_mfma_f32_16x16x32_bf16(pa, vb, acc_o[dt], 0, 0, 0);
      }
    }
  }

#pragma unroll
  for (int r = 0; r < 4; ++r) {
    int row = q0 + w * 16 + lg * 4 + r;
    float logl = __logf(l_r[r]);
#pragma unroll
    for (int dt = 0; dt < 4; ++dt) {
      int d = dt * 16 + lr;
      Og[(((size_t)b * NL + row) * NH + h) * ND + d] =
          __logf(acc_o[dt][r]) - logl + vmx[d];
    }
  }
}

extern "C" void kernel_launch(void* const* d_in, const int* in_sizes, int n_in,
                              void* d_out, int out_size, void* d_ws, size_t ws_size,
                              hipStream_t stream) {
  (void)in_sizes; (void)n_in; (void)out_size;
  const float* Q = (const float*)d_in[0];
  const float* K = (const float*)d_in[1];
  const float* V = (const float*)d_in[2];
  float* out = (float*)d_out;

  float* vmax = (float*)d_ws;                         // 4KB (slow path only)
  float* part = (float*)((char*)d_ws + 4096);         // 64KB (slow path only)
  const size_t kimg_off = 1u << 20;                   // 1MB
  const size_t vimg_off = (size_t)9u << 20;           // 9MB
  const size_t img_bytes = (size_t)16 * NT * TILE_B;  // 8MB each
  bool fast = ws_size >= vimg_off + img_bytes;

  if (fast) {
    ushort_t* kimg = (ushort_t*)((char*)d_ws + kimg_off);
    ushort_t* vimg = (ushort_t*)((char*)d_ws + vimg_off);
    kvprep<<<dim3(1024), dim3(256), 0, stream>>>(K, V, kimg, vimg);
    laser_fast<<<dim3(256), dim3(512), 0, stream>>>(Q, kimg, vimg, out);
  } else {
    vmax_partial<<<dim3(256), dim3(256), 0, stream>>>(V, part);
    vmax_reduce<<<dim3(16), dim3(64), 0, stream>>>(part, vmax);
    laser_slow<<<dim3(1024), dim3(256), 0, stream>>>(Q, K, V, vmax, out);
  }
}